// Round 1
// baseline (497.091 us; speedup 1.0000x reference)
//
#include <hip/hip_runtime.h>
#include <math.h>

#define B_ 8
#define N_ 1024
#define F_ 768
#define H_ 12
#define DH_ 64
#define MH_ 3072
#define MROWS (B_ * N_)

typedef unsigned short u16;
typedef unsigned int u32;
typedef __bf16 bf16x8 __attribute__((ext_vector_type(8)));
typedef float f32x4 __attribute__((ext_vector_type(4)));

__device__ inline f32x4 mfma16(bf16x8 a, bf16x8 b, f32x4 c) {
  return __builtin_amdgcn_mfma_f32_16x16x32_bf16(a, b, c, 0, 0, 0);
}

__device__ inline u16 f2bu(float f) {  // float -> bf16 bits, RNE
  u32 b = __builtin_bit_cast(u32, f);
  b += 0x7fffu + ((b >> 16) & 1u);
  return (u16)(b >> 16);
}
__device__ inline float bu2f(u16 u) {
  u32 x = ((u32)u) << 16;
  return __builtin_bit_cast(float, x);
}
__device__ inline float gelu_exact(float x) {
  return 0.5f * x * (1.0f + erff(x * 0.70710678118654752f));
}

// ---------------- transpose + convert to bf16: out[c][r] = in[r][c] ----------
__device__ inline float ldf(const float* p) { return *p; }
__device__ inline float ldf(const u16* p) { return bu2f(*p); }

template <typename Tin>
__global__ __launch_bounds__(256) void transpose_bf16(
    const Tin* __restrict__ in, u16* __restrict__ out, int R, int C) {
  __shared__ float tile[64][65];
  size_t base = (size_t)blockIdx.z * (size_t)R * (size_t)C;
  int r0 = blockIdx.y << 6, c0 = blockIdx.x << 6;
  int t = threadIdx.x;
#pragma unroll
  for (int i = 0; i < 16; ++i) {
    int idx = t + (i << 8);
    int r = idx >> 6, c = idx & 63;
    tile[r][c] = ldf(&in[base + (size_t)(r0 + r) * C + (c0 + c)]);
  }
  __syncthreads();
#pragma unroll
  for (int i = 0; i < 16; ++i) {
    int idx = t + (i << 8);
    int rr = idx >> 6, cc = idx & 63;
    out[base + (size_t)(c0 + rr) * R + (r0 + cc)] = f2bu(tile[cc][rr]);
  }
}

// ---------------- LayerNorm (row=768) fp32 -> bf16 ---------------------------
__global__ __launch_bounds__(256) void ln_to_bf16(
    const float* __restrict__ X, const float* __restrict__ gw,
    const float* __restrict__ bw, u16* __restrict__ Y) {
  int row = blockIdx.x;
  int t = threadIdx.x;
  const float* xr = X + (size_t)row * F_;
  float v0 = xr[t], v1 = xr[t + 256], v2 = xr[t + 512];
  float s = v0 + v1 + v2;
  float ss = v0 * v0 + v1 * v1 + v2 * v2;
#pragma unroll
  for (int off = 1; off < 64; off <<= 1) {
    s += __shfl_xor(s, off, 64);
    ss += __shfl_xor(ss, off, 64);
  }
  __shared__ float red[8];
  int wid = t >> 6, lane = t & 63;
  if (lane == 0) { red[wid] = s; red[4 + wid] = ss; }
  __syncthreads();
  s = red[0] + red[1] + red[2] + red[3];
  ss = red[4] + red[5] + red[6] + red[7];
  float mu = s * (1.0f / F_);
  float var = ss * (1.0f / F_) - mu * mu;
  float rstd = rsqrtf(var + 1e-5f);
  u16* yr = Y + (size_t)row * F_;
  yr[t] = f2bu((v0 - mu) * rstd * gw[t] + bw[t]);
  yr[t + 256] = f2bu((v1 - mu) * rstd * gw[t + 256] + bw[t + 256]);
  yr[t + 512] = f2bu((v2 - mu) * rstd * gw[t + 512] + bw[t + 512]);
}

// ---------------- bf16 GEMM: C = A[M,K] * Bt[N,K]^T + bias, fused epilogues --
// MODE 0: QKV  -> bf16 scatter to [B,H,N,DH]
// MODE 1: proj -> fp32 out = acc + bias + resid(x)
// MODE 2: ffn1 -> bf16 gelu(acc + bias)
// MODE 3: ffn2 -> fp32 gelu(acc + bias) + resid(out)
template <int MODE>
__global__ __launch_bounds__(256) void gemm_bt(
    const u16* __restrict__ A, const u16* __restrict__ Bt,
    const float* __restrict__ bias, void* __restrict__ outp,
    const float* __restrict__ resid, int Mdim, int Ndim, int Kdim) {
  __shared__ __attribute__((aligned(16))) u16 As[128][40];
  __shared__ __attribute__((aligned(16))) u16 Bs[128][40];
  int t = threadIdx.x;
  int lane = t & 63, wid = t >> 6;
  int row0 = blockIdx.y << 7, col0 = blockIdx.x << 7;
  int wr = (wid >> 1) << 6, wc = (wid & 1) << 6;
  int lr = lane & 15, lk = (lane >> 4) << 3;
  int rbase = (lane >> 4) << 2;
  f32x4 zero = {0.f, 0.f, 0.f, 0.f};
  f32x4 acc[4][4];
#pragma unroll
  for (int m = 0; m < 4; ++m)
#pragma unroll
    for (int n = 0; n < 4; ++n) acc[m][n] = zero;

  int ar = t >> 2;
  int akc = (t & 3) << 3;

  for (int kt = 0; kt < Kdim; kt += 32) {
    __syncthreads();
    *(uint4*)&As[ar][akc] = *(const uint4*)&A[(size_t)(row0 + ar) * Kdim + kt + akc];
    *(uint4*)&As[ar + 64][akc] = *(const uint4*)&A[(size_t)(row0 + ar + 64) * Kdim + kt + akc];
    *(uint4*)&Bs[ar][akc] = *(const uint4*)&Bt[(size_t)(col0 + ar) * Kdim + kt + akc];
    *(uint4*)&Bs[ar + 64][akc] = *(const uint4*)&Bt[(size_t)(col0 + ar + 64) * Kdim + kt + akc];
    __syncthreads();
    bf16x8 af[4], bfr[4];
#pragma unroll
    for (int m = 0; m < 4; ++m) af[m] = *(const bf16x8*)&As[wr + (m << 4) + lr][lk];
#pragma unroll
    for (int n = 0; n < 4; ++n) bfr[n] = *(const bf16x8*)&Bs[wc + (n << 4) + lr][lk];
#pragma unroll
    for (int m = 0; m < 4; ++m)
#pragma unroll
      for (int n = 0; n < 4; ++n) acc[m][n] = mfma16(af[m], bfr[n], acc[m][n]);
  }

#pragma unroll
  for (int n = 0; n < 4; ++n) {
    int col = col0 + wc + (n << 4) + lr;
    float bc = bias[col];
#pragma unroll
    for (int m = 0; m < 4; ++m) {
#pragma unroll
      for (int r = 0; r < 4; ++r) {
        int row = row0 + wr + (m << 4) + rbase + r;
        float val = acc[m][n][r] + bc;
        if constexpr (MODE == 0) {
          int b = row >> 10, nn = row & 1023;
          int h = col >> 6, dh = col & 63;
          ((u16*)outp)[((((size_t)b * H_ + h) << 10) + nn) * DH_ + dh] = f2bu(val);
        } else if constexpr (MODE == 1) {
          val += resid[(size_t)row * Ndim + col];
          ((float*)outp)[(size_t)row * Ndim + col] = val;
        } else if constexpr (MODE == 2) {
          ((u16*)outp)[(size_t)row * Ndim + col] = f2bu(gelu_exact(val));
        } else {
          val = gelu_exact(val) + resid[(size_t)row * Ndim + col];
          ((float*)outp)[(size_t)row * Ndim + col] = val;
        }
      }
    }
  }
}

// ---------------- flash attention: Q,K [bh][N][64] bf16, Vt [bh][64][N] bf16 -
// out: attn [B*N][F] bf16 (col = h*64+dh). softmax scale = 1/sqrt(F)=1/sqrt(768)
__global__ __launch_bounds__(256) void attn_fwd(
    const u16* __restrict__ Q, const u16* __restrict__ K,
    const u16* __restrict__ Vt, u16* __restrict__ Aout) {
  __shared__ __attribute__((aligned(16))) u16 Ks[128][72];
  __shared__ __attribute__((aligned(16))) u16 Vs[64][136];
  __shared__ __attribute__((aligned(16))) u16 Ps[4][32][136];
  int t = threadIdx.x, lane = t & 63, wid = t >> 6;
  int bh = blockIdx.y;
  int q0 = (blockIdx.x << 7) + (wid << 5);
  int lr = lane & 15, lk = (lane >> 4) << 3;
  int rbase = (lane >> 4) << 2;
  const float scale = 0.03608439182435161f;  // 1/sqrt(768)
  const float LOG2E = 1.4426950408889634f;

  bf16x8 qf[2][2];
#pragma unroll
  for (int m = 0; m < 2; ++m)
#pragma unroll
    for (int ks = 0; ks < 2; ++ks)
      qf[m][ks] = *(const bf16x8*)&Q[((size_t)bh * N_ + q0 + (m << 4) + lr) * DH_ + (ks << 5) + lk];

  float mrun[2][4], lrun[2][4];
  f32x4 zero = {0.f, 0.f, 0.f, 0.f};
  f32x4 Oacc[2][4];
#pragma unroll
  for (int m = 0; m < 2; ++m) {
#pragma unroll
    for (int r = 0; r < 4; ++r) { mrun[m][r] = -3.0e38f; lrun[m][r] = 0.f; }
#pragma unroll
    for (int nd = 0; nd < 4; ++nd) Oacc[m][nd] = zero;
  }

  for (int kt = 0; kt < 8; ++kt) {
    __syncthreads();
#pragma unroll
    for (int p = 0; p < 4; ++p) {
      int c = t + (p << 8);
      int r = c >> 3, kc = (c & 7) << 3;
      *(uint4*)&Ks[r][kc] = *(const uint4*)&K[((size_t)bh * N_ + (kt << 7) + r) * DH_ + kc];
      int r2 = c >> 4, kc2 = (c & 15) << 3;
      *(uint4*)&Vs[r2][kc2] = *(const uint4*)&Vt[((size_t)bh * DH_ + r2) * N_ + (kt << 7) + kc2];
    }
    __syncthreads();

    f32x4 s[2][8];
#pragma unroll
    for (int m = 0; m < 2; ++m)
#pragma unroll
      for (int n = 0; n < 8; ++n) s[m][n] = zero;
#pragma unroll
    for (int ks = 0; ks < 2; ++ks) {
      bf16x8 kf[8];
#pragma unroll
      for (int n = 0; n < 8; ++n) kf[n] = *(const bf16x8*)&Ks[(n << 4) + lr][(ks << 5) + lk];
#pragma unroll
      for (int m = 0; m < 2; ++m)
#pragma unroll
        for (int n = 0; n < 8; ++n) s[m][n] = mfma16(qf[m][ks], kf[n], s[m][n]);
    }

    float mnew[2][4], alpha[2][4], rsum[2][4];
#pragma unroll
    for (int m = 0; m < 2; ++m)
#pragma unroll
      for (int r = 0; r < 4; ++r) {
        float mx = mrun[m][r];
#pragma unroll
        for (int n = 0; n < 8; ++n) mx = fmaxf(mx, s[m][n][r] * scale);
#pragma unroll
        for (int off = 1; off < 16; off <<= 1) mx = fmaxf(mx, __shfl_xor(mx, off, 64));
        mnew[m][r] = mx;
        alpha[m][r] = exp2f((mrun[m][r] - mx) * LOG2E);
        mrun[m][r] = mx;
        rsum[m][r] = 0.f;
      }
#pragma unroll
    for (int m = 0; m < 2; ++m)
#pragma unroll
      for (int n = 0; n < 8; ++n)
#pragma unroll
        for (int r = 0; r < 4; ++r) {
          float p = exp2f((s[m][n][r] * scale - mnew[m][r]) * LOG2E);
          rsum[m][r] += p;
          Ps[wid][(m << 4) + rbase + r][(n << 4) + lr] = f2bu(p);
        }
#pragma unroll
    for (int m = 0; m < 2; ++m)
#pragma unroll
      for (int r = 0; r < 4; ++r) {
        float rv = rsum[m][r];
#pragma unroll
        for (int off = 1; off < 16; off <<= 1) rv += __shfl_xor(rv, off, 64);
        lrun[m][r] = lrun[m][r] * alpha[m][r] + rv;
#pragma unroll
        for (int nd = 0; nd < 4; ++nd) Oacc[m][nd][r] *= alpha[m][r];
      }
    __syncthreads();
#pragma unroll
    for (int ks = 0; ks < 4; ++ks) {
      bf16x8 pf[2], vf[4];
#pragma unroll
      for (int m = 0; m < 2; ++m) pf[m] = *(const bf16x8*)&Ps[wid][(m << 4) + lr][(ks << 5) + lk];
#pragma unroll
      for (int nd = 0; nd < 4; ++nd) vf[nd] = *(const bf16x8*)&Vs[(nd << 4) + lr][(ks << 5) + lk];
#pragma unroll
      for (int m = 0; m < 2; ++m)
#pragma unroll
        for (int nd = 0; nd < 4; ++nd) Oacc[m][nd] = mfma16(pf[m], vf[nd], Oacc[m][nd]);
    }
  }

  int b = bh / H_, h = bh % H_;
#pragma unroll
  for (int m = 0; m < 2; ++m)
#pragma unroll
    for (int r = 0; r < 4; ++r) {
      float inv = 1.0f / lrun[m][r];
      int row = q0 + (m << 4) + rbase + r;
      size_t orow = ((size_t)b * N_ + row) * F_ + (size_t)h * DH_;
#pragma unroll
      for (int nd = 0; nd < 4; ++nd)
        Aout[orow + (nd << 4) + lr] = f2bu(Oacc[m][nd][r] * inv);
    }
}

extern "C" void kernel_launch(void* const* d_in, const int* in_sizes, int n_in,
                              void* d_out, int out_size, void* d_ws, size_t ws_size,
                              hipStream_t stream) {
  (void)in_sizes; (void)n_in; (void)out_size; (void)ws_size;
  const float* x   = (const float*)d_in[0];
  const float* Wq  = (const float*)d_in[1];
  const float* bq  = (const float*)d_in[2];
  const float* Wk  = (const float*)d_in[3];
  const float* bk  = (const float*)d_in[4];
  const float* Wv  = (const float*)d_in[5];
  const float* bv  = (const float*)d_in[6];
  const float* Wo  = (const float*)d_in[7];
  const float* bo  = (const float*)d_in[8];
  const float* g1  = (const float*)d_in[9];
  const float* bn1 = (const float*)d_in[10];
  const float* g2  = (const float*)d_in[11];
  const float* bn2 = (const float*)d_in[12];
  const float* W1  = (const float*)d_in[13];
  const float* b1  = (const float*)d_in[14];
  const float* W2  = (const float*)d_in[15];
  const float* b2  = (const float*)d_in[16];

  char* ws = (char*)d_ws;
  size_t off = 0;
  auto alloc = [&](size_t bytes) {
    char* p = ws + off;
    off += (bytes + 255) & ~(size_t)255;
    return p;
  };
  u16* Wqt = (u16*)alloc((size_t)F_ * F_ * 2);
  u16* Wkt = (u16*)alloc((size_t)F_ * F_ * 2);
  u16* Wvt = (u16*)alloc((size_t)F_ * F_ * 2);
  u16* Wot = (u16*)alloc((size_t)F_ * F_ * 2);
  u16* W1t = (u16*)alloc((size_t)MH_ * F_ * 2);
  u16* W2t = (u16*)alloc((size_t)MH_ * F_ * 2);
  u16* xn  = (u16*)alloc((size_t)MROWS * F_ * 2);            // reused as hn
  u16* qb  = (u16*)alloc((size_t)B_ * H_ * N_ * DH_ * 2);    // 12582912 B
  u16* kb  = (u16*)alloc((size_t)B_ * H_ * N_ * DH_ * 2);
  u16* vb  = (u16*)alloc((size_t)B_ * H_ * N_ * DH_ * 2);
  u16* vt  = (u16*)alloc((size_t)B_ * H_ * N_ * DH_ * 2);
  u16* attn = (u16*)alloc((size_t)MROWS * F_ * 2);
  float* outb = (float*)alloc((size_t)MROWS * F_ * 4);
  u16* h1 = qb;   // q/k/v/vt region == 50331648 B == 8192*3072*2, free by then
  u16* hn = xn;

  dim3 blk(256);
  transpose_bf16<float><<<dim3(12, 12, 1), blk, 0, stream>>>(Wq, Wqt, F_, F_);
  transpose_bf16<float><<<dim3(12, 12, 1), blk, 0, stream>>>(Wk, Wkt, F_, F_);
  transpose_bf16<float><<<dim3(12, 12, 1), blk, 0, stream>>>(Wv, Wvt, F_, F_);
  transpose_bf16<float><<<dim3(12, 12, 1), blk, 0, stream>>>(Wo, Wot, F_, F_);
  transpose_bf16<float><<<dim3(48, 12, 1), blk, 0, stream>>>(W1, W1t, F_, MH_);
  transpose_bf16<float><<<dim3(12, 48, 1), blk, 0, stream>>>(W2, W2t, MH_, F_);
  ln_to_bf16<<<dim3(MROWS), blk, 0, stream>>>(x, g1, bn1, xn);
  gemm_bt<0><<<dim3(6, 64), blk, 0, stream>>>(xn, Wqt, bq, qb, nullptr, MROWS, F_, F_);
  gemm_bt<0><<<dim3(6, 64), blk, 0, stream>>>(xn, Wkt, bk, kb, nullptr, MROWS, F_, F_);
  gemm_bt<0><<<dim3(6, 64), blk, 0, stream>>>(xn, Wvt, bv, vb, nullptr, MROWS, F_, F_);
  transpose_bf16<u16><<<dim3(1, 16, 96), blk, 0, stream>>>(vb, vt, N_, DH_);
  attn_fwd<<<dim3(8, 96), blk, 0, stream>>>(qb, kb, vt, attn);
  gemm_bt<1><<<dim3(6, 64), blk, 0, stream>>>(attn, Wot, bo, outb, x, MROWS, F_, F_);
  ln_to_bf16<<<dim3(MROWS), blk, 0, stream>>>(outb, g2, bn2, hn);
  gemm_bt<2><<<dim3(24, 64), blk, 0, stream>>>(hn, W1t, b1, h1, nullptr, MROWS, MH_, F_);
  gemm_bt<3><<<dim3(6, 64), blk, 0, stream>>>(h1, W2t, b2, d_out, outb, MROWS, F_, MH_);
}

// Round 2
// 371.187 us; speedup vs baseline: 1.3392x; 1.3392x over previous
//
#include <hip/hip_runtime.h>
#include <math.h>

#define B_ 8
#define N_ 1024
#define F_ 768
#define H_ 12
#define DH_ 64
#define MH_ 3072
#define MROWS (B_ * N_)

typedef unsigned short u16;
typedef unsigned int u32;
typedef __bf16 bf16x8 __attribute__((ext_vector_type(8)));
typedef float f32x4 __attribute__((ext_vector_type(4)));

__device__ inline f32x4 mfma16(bf16x8 a, bf16x8 b, f32x4 c) {
  return __builtin_amdgcn_mfma_f32_16x16x32_bf16(a, b, c, 0, 0, 0);
}

__device__ inline u16 f2bu(float f) {  // float -> bf16 bits, RNE
  u32 b = __builtin_bit_cast(u32, f);
  b += 0x7fffu + ((b >> 16) & 1u);
  return (u16)(b >> 16);
}
__device__ inline float bu2f(u16 u) {
  u32 x = ((u32)u) << 16;
  return __builtin_bit_cast(float, x);
}
__device__ inline float gelu_exact(float x) {
  return 0.5f * x * (1.0f + erff(x * 0.70710678118654752f));
}

#define AS1 __attribute__((address_space(1)))
#define AS3 __attribute__((address_space(3)))
__device__ inline void glds16(const void* g, void* l) {
  __builtin_amdgcn_global_load_lds((const AS1 void*)g, (AS3 void*)l, 16, 0, 0);
}

// ---------------- transpose + convert to bf16: out[c][r] = in[r][c] ----------
__device__ inline float ldf(const float* p) { return *p; }
__device__ inline float ldf(const u16* p) { return bu2f(*p); }

template <typename Tin>
__global__ __launch_bounds__(256) void transpose_bf16(
    const Tin* __restrict__ in, u16* __restrict__ out, int R, int C) {
  __shared__ float tile[64][65];
  size_t base = (size_t)blockIdx.z * (size_t)R * (size_t)C;
  int r0 = blockIdx.y << 6, c0 = blockIdx.x << 6;
  int t = threadIdx.x;
#pragma unroll
  for (int i = 0; i < 16; ++i) {
    int idx = t + (i << 8);
    int r = idx >> 6, c = idx & 63;
    tile[r][c] = ldf(&in[base + (size_t)(r0 + r) * C + (c0 + c)]);
  }
  __syncthreads();
#pragma unroll
  for (int i = 0; i < 16; ++i) {
    int idx = t + (i << 8);
    int rr = idx >> 6, cc = idx & 63;
    out[base + (size_t)(c0 + rr) * R + (r0 + cc)] = f2bu(tile[cc][rr]);
  }
}

// ---------------- LayerNorm (row=768) fp32 -> bf16 ---------------------------
__global__ __launch_bounds__(256) void ln_to_bf16(
    const float* __restrict__ X, const float* __restrict__ gw,
    const float* __restrict__ bw, u16* __restrict__ Y) {
  int row = blockIdx.x;
  int t = threadIdx.x;
  const float* xr = X + (size_t)row * F_;
  float v0 = xr[t], v1 = xr[t + 256], v2 = xr[t + 512];
  float s = v0 + v1 + v2;
  float ss = v0 * v0 + v1 * v1 + v2 * v2;
#pragma unroll
  for (int off = 1; off < 64; off <<= 1) {
    s += __shfl_xor(s, off, 64);
    ss += __shfl_xor(ss, off, 64);
  }
  __shared__ float red[8];
  int wid = t >> 6, lane = t & 63;
  if (lane == 0) { red[wid] = s; red[4 + wid] = ss; }
  __syncthreads();
  s = red[0] + red[1] + red[2] + red[3];
  ss = red[4] + red[5] + red[6] + red[7];
  float mu = s * (1.0f / F_);
  float var = ss * (1.0f / F_) - mu * mu;
  float rstd = rsqrtf(var + 1e-5f);
  u16* yr = Y + (size_t)row * F_;
  yr[t] = f2bu((v0 - mu) * rstd * gw[t] + bw[t]);
  yr[t + 256] = f2bu((v1 - mu) * rstd * gw[t + 256] + bw[t + 256]);
  yr[t + 512] = f2bu((v2 - mu) * rstd * gw[t + 512] + bw[t + 512]);
}

// ---------------- bf16 GEMM (m97 structure): C = A[M,K] * Bt[N,K]^T ----------
// global_load_lds width-16 staging into linear LDS [128][32].
// MODE 0: QKV  -> bf16 scatter to [B,H,N,DH], * qscale
// MODE 1: proj -> fp32 out = acc + bias + resid(x)
// MODE 2: ffn1 -> bf16 gelu(acc + bias)
// MODE 3: ffn2 -> fp32 gelu(acc + bias) + resid(out)
template <int MODE>
__global__ __launch_bounds__(256) void gemm_bt(
    const u16* __restrict__ A, const u16* __restrict__ Bt,
    const float* __restrict__ bias, void* __restrict__ outp,
    const float* __restrict__ resid, int Mdim, int Ndim, int Kdim,
    float qscale) {
  __shared__ __attribute__((aligned(16))) u16 As[128][32];
  __shared__ __attribute__((aligned(16))) u16 Bs[128][32];
  int t = threadIdx.x;
  int lane = t & 63, wid = t >> 6;
  int row0 = blockIdx.y << 7, col0 = blockIdx.x << 7;
  int wr = (wid >> 1) << 6, wc = (wid & 1) << 6;
  int lr = lane & 15, lk = (lane >> 4) << 3;
  int rbase = (lane >> 4) << 2;
  f32x4 zero = {0.f, 0.f, 0.f, 0.f};
  f32x4 acc[4][4];
#pragma unroll
  for (int m = 0; m < 4; ++m)
#pragma unroll
    for (int n = 0; n < 4; ++n) acc[m][n] = zero;

  // staging geometry: byte off = wid*1024 + lane*16 (+4096 for i=1)
  int o0 = (wid << 10) + (lane << 4);
  int srow = o0 >> 6;            // 0..63
  int scol = (o0 & 63) >> 1;     // element col 0,8,16,24
  const u16* Ag = A + (size_t)(row0 + srow) * Kdim + scol;
  const u16* Bg = Bt + (size_t)(col0 + srow) * Kdim + scol;
  char* AsB = (char*)&As[0][0] + (wid << 10);
  char* BsB = (char*)&Bs[0][0] + (wid << 10);
  size_t half = (size_t)64 * Kdim;

  for (int kt = 0; kt < Kdim; kt += 32) {
    __syncthreads();
    glds16(Ag + kt, AsB);
    glds16(Ag + kt + half, AsB + 4096);
    glds16(Bg + kt, BsB);
    glds16(Bg + kt + half, BsB + 4096);
    __syncthreads();
    bf16x8 af[4], bfr[4];
#pragma unroll
    for (int m = 0; m < 4; ++m) af[m] = *(const bf16x8*)&As[wr + (m << 4) + lr][lk];
#pragma unroll
    for (int n = 0; n < 4; ++n) bfr[n] = *(const bf16x8*)&Bs[wc + (n << 4) + lr][lk];
#pragma unroll
    for (int m = 0; m < 4; ++m)
#pragma unroll
      for (int n = 0; n < 4; ++n) acc[m][n] = mfma16(af[m], bfr[n], acc[m][n]);
  }

#pragma unroll
  for (int n = 0; n < 4; ++n) {
    int col = col0 + wc + (n << 4) + lr;
    float bc = bias[col];
#pragma unroll
    for (int m = 0; m < 4; ++m) {
#pragma unroll
      for (int r = 0; r < 4; ++r) {
        int row = row0 + wr + (m << 4) + rbase + r;
        float val = acc[m][n][r] + bc;
        if constexpr (MODE == 0) {
          int b = row >> 10, nn = row & 1023;
          int h = col >> 6, dh = col & 63;
          ((u16*)outp)[((((size_t)b * H_ + h) << 10) + nn) * DH_ + dh] = f2bu(val * qscale);
        } else if constexpr (MODE == 1) {
          val += resid[(size_t)row * Ndim + col];
          ((float*)outp)[(size_t)row * Ndim + col] = val;
        } else if constexpr (MODE == 2) {
          ((u16*)outp)[(size_t)row * Ndim + col] = f2bu(gelu_exact(val));
        } else {
          val = gelu_exact(val) + resid[(size_t)row * Ndim + col];
          ((float*)outp)[(size_t)row * Ndim + col] = val;
        }
      }
    }
  }
}

// ---------------- flash attention v2: no-max softmax, KV chunk 64 ------------
// Q pre-scaled by 1/sqrt(768)*log2(e) at the QKV GEMM epilogue.
// Q,K [bh][N][64] bf16, Vt [bh][64][N] bf16; out attn [B*N][F] bf16.
__global__ __launch_bounds__(256, 3) void attn_fwd(
    const u16* __restrict__ Q, const u16* __restrict__ K,
    const u16* __restrict__ Vt, u16* __restrict__ Aout) {
  __shared__ __attribute__((aligned(16))) u16 Ks[64][72];
  __shared__ __attribute__((aligned(16))) u16 Vs[64][72];
  __shared__ __attribute__((aligned(16))) u16 Ps[4][32][72];
  int t = threadIdx.x, lane = t & 63, wid = t >> 6;
  int bh = blockIdx.y;
  int q0 = (blockIdx.x << 7) + (wid << 5);
  int lr = lane & 15, lk = (lane >> 4) << 3;
  int rbase = (lane >> 4) << 2;

  bf16x8 qf[2][2];
#pragma unroll
  for (int m = 0; m < 2; ++m)
#pragma unroll
    for (int ks = 0; ks < 2; ++ks)
      qf[m][ks] = *(const bf16x8*)&Q[((size_t)bh * N_ + q0 + (m << 4) + lr) * DH_ + (ks << 5) + lk];

  float lsum[2][4];
  f32x4 zero = {0.f, 0.f, 0.f, 0.f};
  f32x4 Oacc[2][4];
#pragma unroll
  for (int m = 0; m < 2; ++m) {
#pragma unroll
    for (int r = 0; r < 4; ++r) lsum[m][r] = 0.f;
#pragma unroll
    for (int nd = 0; nd < 4; ++nd) Oacc[m][nd] = zero;
  }

  int srow = t >> 3;            // 0..31
  int scol = (t & 7) << 3;      // 0..56
  const u16* Kg = K + ((size_t)bh * N_ + srow) * DH_ + scol;
  const u16* Vg = Vt + ((size_t)bh * DH_ + srow) * N_ + scol;

  for (int kt = 0; kt < 16; ++kt) {
    __syncthreads();
    *(uint4*)&Ks[srow][scol]      = *(const uint4*)(Kg + (size_t)(kt << 6) * DH_);
    *(uint4*)&Ks[srow + 32][scol] = *(const uint4*)(Kg + (size_t)((kt << 6) + 32) * DH_);
    *(uint4*)&Vs[srow][scol]      = *(const uint4*)(Vg + (kt << 6));
    *(uint4*)&Vs[srow + 32][scol] = *(const uint4*)(Vg + (size_t)32 * N_ + (kt << 6));
    __syncthreads();

    // QK^T (Q already carries scale*log2e)
    f32x4 s[2][4];
#pragma unroll
    for (int m = 0; m < 2; ++m)
#pragma unroll
      for (int n = 0; n < 4; ++n) s[m][n] = zero;
#pragma unroll
    for (int ks = 0; ks < 2; ++ks) {
      bf16x8 kf[4];
#pragma unroll
      for (int n = 0; n < 4; ++n) kf[n] = *(const bf16x8*)&Ks[(n << 4) + lr][(ks << 5) + lk];
#pragma unroll
      for (int m = 0; m < 2; ++m)
#pragma unroll
        for (int n = 0; n < 4; ++n) s[m][n] = mfma16(qf[m][ks], kf[n], s[m][n]);
    }

    // softmax numerator, no max subtraction; deferred row-sum
#pragma unroll
    for (int m = 0; m < 2; ++m)
#pragma unroll
      for (int n = 0; n < 4; ++n)
#pragma unroll
        for (int r = 0; r < 4; ++r) {
          float p = exp2f(s[m][n][r]);
          lsum[m][r] += p;
          Ps[wid][(m << 4) + rbase + r][(n << 4) + lr] = f2bu(p);
        }

    // PV: Ps is wave-private; compiler inserts the RAW lgkmcnt wait
#pragma unroll
    for (int ks = 0; ks < 2; ++ks) {
      bf16x8 pf[2], vf[4];
#pragma unroll
      for (int m = 0; m < 2; ++m) pf[m] = *(const bf16x8*)&Ps[wid][(m << 4) + lr][(ks << 5) + lk];
#pragma unroll
      for (int nd = 0; nd < 4; ++nd) vf[nd] = *(const bf16x8*)&Vs[(nd << 4) + lr][(ks << 5) + lk];
#pragma unroll
      for (int m = 0; m < 2; ++m)
#pragma unroll
        for (int nd = 0; nd < 4; ++nd) Oacc[m][nd] = mfma16(pf[m], vf[nd], Oacc[m][nd]);
    }
  }

  int b = bh / H_, h = bh % H_;
#pragma unroll
  for (int m = 0; m < 2; ++m)
#pragma unroll
    for (int r = 0; r < 4; ++r) {
      float sv = lsum[m][r];
#pragma unroll
      for (int off = 1; off < 16; off <<= 1) sv += __shfl_xor(sv, off, 64);
      float inv = 1.0f / sv;
      int row = q0 + (m << 4) + rbase + r;
      size_t orow = ((size_t)b * N_ + row) * F_ + (size_t)h * DH_;
#pragma unroll
      for (int nd = 0; nd < 4; ++nd)
        Aout[orow + (nd << 4) + lr] = f2bu(Oacc[m][nd][r] * inv);
    }
}

extern "C" void kernel_launch(void* const* d_in, const int* in_sizes, int n_in,
                              void* d_out, int out_size, void* d_ws, size_t ws_size,
                              hipStream_t stream) {
  (void)in_sizes; (void)n_in; (void)out_size; (void)ws_size;
  const float* x   = (const float*)d_in[0];
  const float* Wq  = (const float*)d_in[1];
  const float* bq  = (const float*)d_in[2];
  const float* Wk  = (const float*)d_in[3];
  const float* bk  = (const float*)d_in[4];
  const float* Wv  = (const float*)d_in[5];
  const float* bv  = (const float*)d_in[6];
  const float* Wo  = (const float*)d_in[7];
  const float* bo  = (const float*)d_in[8];
  const float* g1  = (const float*)d_in[9];
  const float* bn1 = (const float*)d_in[10];
  const float* g2  = (const float*)d_in[11];
  const float* bn2 = (const float*)d_in[12];
  const float* W1  = (const float*)d_in[13];
  const float* b1  = (const float*)d_in[14];
  const float* W2  = (const float*)d_in[15];
  const float* b2  = (const float*)d_in[16];

  char* ws = (char*)d_ws;
  size_t off = 0;
  auto alloc = [&](size_t bytes) {
    char* p = ws + off;
    off += (bytes + 255) & ~(size_t)255;
    return p;
  };
  u16* Wqt = (u16*)alloc((size_t)F_ * F_ * 2);
  u16* Wkt = (u16*)alloc((size_t)F_ * F_ * 2);
  u16* Wvt = (u16*)alloc((size_t)F_ * F_ * 2);
  u16* Wot = (u16*)alloc((size_t)F_ * F_ * 2);
  u16* W1t = (u16*)alloc((size_t)MH_ * F_ * 2);
  u16* W2t = (u16*)alloc((size_t)MH_ * F_ * 2);
  u16* xn  = (u16*)alloc((size_t)MROWS * F_ * 2);            // reused as hn
  u16* qb  = (u16*)alloc((size_t)B_ * H_ * N_ * DH_ * 2);    // 12582912 B
  u16* kb  = (u16*)alloc((size_t)B_ * H_ * N_ * DH_ * 2);
  u16* vb  = (u16*)alloc((size_t)B_ * H_ * N_ * DH_ * 2);
  u16* vt  = (u16*)alloc((size_t)B_ * H_ * N_ * DH_ * 2);
  u16* attn = (u16*)alloc((size_t)MROWS * F_ * 2);
  float* outb = (float*)alloc((size_t)MROWS * F_ * 4);
  u16* h1 = qb;   // q/k/v/vt region == 50331648 B == 8192*3072*2, free by then
  u16* hn = xn;

  // fold softmax scale and log2(e) into Q: 1/sqrt(768) * 1.4426950408889634
  const float QSCALE = 0.052058773227f;

  dim3 blk(256);
  transpose_bf16<float><<<dim3(12, 12, 1), blk, 0, stream>>>(Wq, Wqt, F_, F_);
  transpose_bf16<float><<<dim3(12, 12, 1), blk, 0, stream>>>(Wk, Wkt, F_, F_);
  transpose_bf16<float><<<dim3(12, 12, 1), blk, 0, stream>>>(Wv, Wvt, F_, F_);
  transpose_bf16<float><<<dim3(12, 12, 1), blk, 0, stream>>>(Wo, Wot, F_, F_);
  transpose_bf16<float><<<dim3(48, 12, 1), blk, 0, stream>>>(W1, W1t, F_, MH_);
  transpose_bf16<float><<<dim3(12, 48, 1), blk, 0, stream>>>(W2, W2t, MH_, F_);
  ln_to_bf16<<<dim3(MROWS), blk, 0, stream>>>(x, g1, bn1, xn);
  gemm_bt<0><<<dim3(6, 64), blk, 0, stream>>>(xn, Wqt, bq, qb, nullptr, MROWS, F_, F_, QSCALE);
  gemm_bt<0><<<dim3(6, 64), blk, 0, stream>>>(xn, Wkt, bk, kb, nullptr, MROWS, F_, F_, 1.0f);
  gemm_bt<0><<<dim3(6, 64), blk, 0, stream>>>(xn, Wvt, bv, vb, nullptr, MROWS, F_, F_, 1.0f);
  transpose_bf16<u16><<<dim3(1, 16, 96), blk, 0, stream>>>(vb, vt, N_, DH_);
  attn_fwd<<<dim3(8, 96), blk, 0, stream>>>(qb, kb, vt, attn);
  gemm_bt<1><<<dim3(6, 64), blk, 0, stream>>>(attn, Wot, bo, outb, x, MROWS, F_, F_, 1.0f);
  ln_to_bf16<<<dim3(MROWS), blk, 0, stream>>>(outb, g2, bn2, hn);
  gemm_bt<2><<<dim3(24, 64), blk, 0, stream>>>(hn, W1t, b1, h1, nullptr, MROWS, MH_, F_, 1.0f);
  gemm_bt<3><<<dim3(6, 64), blk, 0, stream>>>(h1, W2t, b2, d_out, outb, MROWS, F_, MH_, 1.0f);
}

// Round 3
// 318.712 us; speedup vs baseline: 1.5597x; 1.1646x over previous
//
#include <hip/hip_runtime.h>
#include <math.h>

#define B_ 8
#define N_ 1024
#define F_ 768
#define H_ 12
#define DH_ 64
#define MH_ 3072
#define MROWS (B_ * N_)

typedef unsigned short u16;
typedef unsigned int u32;
typedef __bf16 bf16x8 __attribute__((ext_vector_type(8)));
typedef float f32x4 __attribute__((ext_vector_type(4)));

__device__ inline f32x4 mfma16(bf16x8 a, bf16x8 b, f32x4 c) {
  return __builtin_amdgcn_mfma_f32_16x16x32_bf16(a, b, c, 0, 0, 0);
}

__device__ inline u16 f2bu(float f) {  // float -> bf16 bits, RNE
  u32 b = __builtin_bit_cast(u32, f);
  b += 0x7fffu + ((b >> 16) & 1u);
  return (u16)(b >> 16);
}
__device__ inline float bu2f(u16 u) {
  u32 x = ((u32)u) << 16;
  return __builtin_bit_cast(float, x);
}
__device__ inline float gelu_exact(float x) {
  return 0.5f * x * (1.0f + erff(x * 0.70710678118654752f));
}

#define AS1 __attribute__((address_space(1)))
#define AS3 __attribute__((address_space(3)))
__device__ inline void glds16(const void* g, void* l) {
  __builtin_amdgcn_global_load_lds((const AS1 void*)g, (AS3 void*)l, 16, 0, 0);
}

// ---------------- transpose + convert to bf16: out[c][r] = in[r][c] ----------
__device__ inline float ldf(const float* p) { return *p; }
__device__ inline float ldf(const u16* p) { return bu2f(*p); }

template <typename Tin>
__global__ __launch_bounds__(256) void transpose_bf16(
    const Tin* __restrict__ in, u16* __restrict__ out, int R, int C) {
  __shared__ float tile[64][65];
  size_t ibase = (size_t)blockIdx.z * (size_t)R * (size_t)C;
  size_t obase = (size_t)blockIdx.z * (size_t)R * (size_t)C;
  int r0 = blockIdx.y << 6, c0 = blockIdx.x << 6;
  int t = threadIdx.x;
#pragma unroll
  for (int i = 0; i < 16; ++i) {
    int idx = t + (i << 8);
    int r = idx >> 6, c = idx & 63;
    tile[r][c] = ldf(&in[ibase + (size_t)(r0 + r) * C + (c0 + c)]);
  }
  __syncthreads();
#pragma unroll
  for (int i = 0; i < 16; ++i) {
    int idx = t + (i << 8);
    int rr = idx >> 6, cc = idx & 63;
    out[obase + (size_t)(c0 + rr) * R + (r0 + cc)] = f2bu(tile[cc][rr]);
  }
}

// ---------------- concat 3 bias vectors [768] -> [2304] ----------------------
__global__ __launch_bounds__(256) void concat_bias(
    const float* __restrict__ a, const float* __restrict__ b,
    const float* __restrict__ c, float* __restrict__ o) {
  int i = blockIdx.x * 256 + threadIdx.x;
  if (i < 768) o[i] = a[i];
  else if (i < 1536) o[i] = b[i - 768];
  else o[i] = c[i - 1536];
}

// ---------------- LayerNorm (row=768) fp32 -> bf16 ---------------------------
__global__ __launch_bounds__(256) void ln_to_bf16(
    const float* __restrict__ X, const float* __restrict__ gw,
    const float* __restrict__ bw, u16* __restrict__ Y) {
  int row = blockIdx.x;
  int t = threadIdx.x;
  const float* xr = X + (size_t)row * F_;
  float v0 = xr[t], v1 = xr[t + 256], v2 = xr[t + 512];
  float s = v0 + v1 + v2;
  float ss = v0 * v0 + v1 * v1 + v2 * v2;
#pragma unroll
  for (int off = 1; off < 64; off <<= 1) {
    s += __shfl_xor(s, off, 64);
    ss += __shfl_xor(ss, off, 64);
  }
  __shared__ float red[8];
  int wid = t >> 6, lane = t & 63;
  if (lane == 0) { red[wid] = s; red[4 + wid] = ss; }
  __syncthreads();
  s = red[0] + red[1] + red[2] + red[3];
  ss = red[4] + red[5] + red[6] + red[7];
  float mu = s * (1.0f / F_);
  float var = ss * (1.0f / F_) - mu * mu;
  float rstd = rsqrtf(var + 1e-5f);
  u16* yr = Y + (size_t)row * F_;
  yr[t] = f2bu((v0 - mu) * rstd * gw[t] + bw[t]);
  yr[t + 256] = f2bu((v1 - mu) * rstd * gw[t + 256] + bw[t + 256]);
  yr[t + 512] = f2bu((v2 - mu) * rstd * gw[t + 512] + bw[t + 512]);
}

// ---------------- bf16 GEMM, 2-phase dbuf + XCD swizzle ----------------------
// C = A[M,K] * Bt[N,K]^T + bias, fused epilogues.
// MODE 0: qkv fused -> bf16 scatter to q/k/v [B,H,N,DH]; q scaled by qscale
// MODE 1: proj -> fp32 out = acc + bias + resid
// MODE 2: ffn1 -> bf16 gelu(acc + bias)
// MODE 3: ffn2 -> fp32 gelu(acc + bias) + resid
template <int MODE>
__global__ __launch_bounds__(256) void gemm_bt(
    const u16* __restrict__ A, const u16* __restrict__ Bt,
    const float* __restrict__ bias, void* __restrict__ outp,
    const float* __restrict__ resid, int Ndim, int Kdim, float qscale) {
  __shared__ __attribute__((aligned(16))) u16 As[2][128][32];
  __shared__ __attribute__((aligned(16))) u16 Bs[2][128][32];
  int t = threadIdx.x;
  int lane = t & 63, wid = t >> 6;

  // XCD-chunked swizzle: each XCD processes a contiguous range of work ids
  int nwg = gridDim.x;
  int q8 = nwg >> 3;
  int bid = blockIdx.x;
  int swz = (bid & 7) * q8 + (bid >> 3);
  int nnt = Ndim >> 7;
  int mt = swz / nnt, nt = swz - mt * nnt;
  int row0 = mt << 7, col0 = nt << 7;

  int wr = (wid >> 1) << 6, wc = (wid & 1) << 6;
  int lr = lane & 15, lk = (lane >> 4) << 3;
  int rbase = (lane >> 4) << 2;
  f32x4 zero = {0.f, 0.f, 0.f, 0.f};
  f32x4 acc[4][4];
#pragma unroll
  for (int m = 0; m < 4; ++m)
#pragma unroll
    for (int n = 0; n < 4; ++n) acc[m][n] = zero;

  // staging: per wave, uniform LDS base wid*1024; HW scatters lane*16
  int o0 = (wid << 10) + (lane << 4);
  int srow = o0 >> 6;            // 0..63
  int scol = (o0 & 63) >> 1;     // 0,8,16,24
  const u16* Ag = A + (size_t)(row0 + srow) * Kdim + scol;
  const u16* Bg = Bt + (size_t)(col0 + srow) * Kdim + scol;
  char* AsB = (char*)&As[0][0][0] + (wid << 10);
  char* BsB = (char*)&Bs[0][0][0] + (wid << 10);
  size_t half = (size_t)64 * Kdim;

  auto STAGE = [&](int buf, int kt) {
    int bo = buf << 13;
    glds16(Ag + kt, AsB + bo);
    glds16(Ag + kt + half, AsB + bo + 4096);
    glds16(Bg + kt, BsB + bo);
    glds16(Bg + kt + half, BsB + bo + 4096);
  };

  STAGE(0, 0);
  __syncthreads();  // drains vmcnt+lgkmcnt
  int nk = Kdim >> 5;
  for (int ki = 0; ki < nk; ++ki) {
    int buf = ki & 1;
    if (ki + 1 < nk) STAGE(buf ^ 1, (ki + 1) << 5);
    bf16x8 af[4], bfr[4];
#pragma unroll
    for (int m = 0; m < 4; ++m) af[m] = *(const bf16x8*)&As[buf][wr + (m << 4) + lr][lk];
#pragma unroll
    for (int n = 0; n < 4; ++n) bfr[n] = *(const bf16x8*)&Bs[buf][wc + (n << 4) + lr][lk];
#pragma unroll
    for (int m = 0; m < 4; ++m)
#pragma unroll
      for (int n = 0; n < 4; ++n) acc[m][n] = mfma16(af[m], bfr[n], acc[m][n]);
    __syncthreads();  // drains vmcnt (next tile staged) + lgkmcnt
  }

#pragma unroll
  for (int n = 0; n < 4; ++n) {
    int col = col0 + wc + (n << 4) + lr;
    float bc = bias[col];
    int sub = 0, hh = 0, dh = 0;
    float sc = 1.0f;
    if constexpr (MODE == 0) {
      sub = (col >= 1536) ? 2 : (col >= 768 ? 1 : 0);
      int c = col - sub * 768;
      hh = c >> 6; dh = c & 63;
      sc = (sub == 0) ? qscale : 1.0f;
    }
#pragma unroll
    for (int m = 0; m < 4; ++m) {
#pragma unroll
      for (int r = 0; r < 4; ++r) {
        int row = row0 + wr + (m << 4) + rbase + r;
        float val = acc[m][n][r] + bc;
        if constexpr (MODE == 0) {
          int b = row >> 10, nn = row & 1023;
          ((u16*)outp)[(size_t)sub * 6291456 +
                       ((((size_t)b * H_ + hh) << 10) + nn) * DH_ + dh] = f2bu(val * sc);
        } else if constexpr (MODE == 1) {
          val += resid[(size_t)row * Ndim + col];
          ((float*)outp)[(size_t)row * Ndim + col] = val;
        } else if constexpr (MODE == 2) {
          ((u16*)outp)[(size_t)row * Ndim + col] = f2bu(gelu_exact(val));
        } else {
          val = gelu_exact(val) + resid[(size_t)row * Ndim + col];
          ((float*)outp)[(size_t)row * Ndim + col] = val;
        }
      }
    }
  }
}

// ---------------- flash attention: no-max softmax, KV chunk 64 ---------------
// Q pre-scaled by 1/sqrt(768)*log2(e). Q,K [bh][N][64], Vt [bh][64][N].
__global__ __launch_bounds__(256, 3) void attn_fwd(
    const u16* __restrict__ Q, const u16* __restrict__ K,
    const u16* __restrict__ Vt, u16* __restrict__ Aout) {
  __shared__ __attribute__((aligned(16))) u16 Ks[64][72];
  __shared__ __attribute__((aligned(16))) u16 Vs[64][72];
  __shared__ __attribute__((aligned(16))) u16 Ps[4][32][72];
  int t = threadIdx.x, lane = t & 63, wid = t >> 6;

  int bid = blockIdx.x;                 // 768 blocks
  int swz = (bid & 7) * 96 + (bid >> 3);
  int bh = swz >> 3;
  int qt = swz & 7;
  int q0 = (qt << 7) + (wid << 5);

  int lr = lane & 15, lk = (lane >> 4) << 3;
  int rbase = (lane >> 4) << 2;

  bf16x8 qf[2][2];
#pragma unroll
  for (int m = 0; m < 2; ++m)
#pragma unroll
    for (int ks = 0; ks < 2; ++ks)
      qf[m][ks] = *(const bf16x8*)&Q[((size_t)bh * N_ + q0 + (m << 4) + lr) * DH_ + (ks << 5) + lk];

  float lsum[2][4];
  f32x4 zero = {0.f, 0.f, 0.f, 0.f};
  f32x4 Oacc[2][4];
#pragma unroll
  for (int m = 0; m < 2; ++m) {
#pragma unroll
    for (int r = 0; r < 4; ++r) lsum[m][r] = 0.f;
#pragma unroll
    for (int nd = 0; nd < 4; ++nd) Oacc[m][nd] = zero;
  }

  int srow = t >> 3;            // 0..31
  int scol = (t & 7) << 3;      // 0..56
  const u16* Kg = K + ((size_t)bh * N_ + srow) * DH_ + scol;
  const u16* Vg = Vt + ((size_t)bh * DH_ + srow) * N_ + scol;

  for (int kt = 0; kt < 16; ++kt) {
    __syncthreads();
    *(uint4*)&Ks[srow][scol]      = *(const uint4*)(Kg + (size_t)(kt << 6) * DH_);
    *(uint4*)&Ks[srow + 32][scol] = *(const uint4*)(Kg + (size_t)((kt << 6) + 32) * DH_);
    *(uint4*)&Vs[srow][scol]      = *(const uint4*)(Vg + (kt << 6));
    *(uint4*)&Vs[srow + 32][scol] = *(const uint4*)(Vg + (size_t)32 * N_ + (kt << 6));
    __syncthreads();

    f32x4 s[2][4];
#pragma unroll
    for (int m = 0; m < 2; ++m)
#pragma unroll
      for (int n = 0; n < 4; ++n) s[m][n] = zero;
#pragma unroll
    for (int ks = 0; ks < 2; ++ks) {
      bf16x8 kf[4];
#pragma unroll
      for (int n = 0; n < 4; ++n) kf[n] = *(const bf16x8*)&Ks[(n << 4) + lr][(ks << 5) + lk];
#pragma unroll
      for (int m = 0; m < 2; ++m)
#pragma unroll
        for (int n = 0; n < 4; ++n) s[m][n] = mfma16(qf[m][ks], kf[n], s[m][n]);
    }

#pragma unroll
    for (int m = 0; m < 2; ++m)
#pragma unroll
      for (int n = 0; n < 4; ++n)
#pragma unroll
        for (int r = 0; r < 4; ++r) {
          float p = exp2f(s[m][n][r]);
          lsum[m][r] += p;
          Ps[wid][(m << 4) + rbase + r][(n << 4) + lr] = f2bu(p);
        }

#pragma unroll
    for (int ks = 0; ks < 2; ++ks) {
      bf16x8 pf[2], vf[4];
#pragma unroll
      for (int m = 0; m < 2; ++m) pf[m] = *(const bf16x8*)&Ps[wid][(m << 4) + lr][(ks << 5) + lk];
#pragma unroll
      for (int nd = 0; nd < 4; ++nd) vf[nd] = *(const bf16x8*)&Vs[(nd << 4) + lr][(ks << 5) + lk];
#pragma unroll
      for (int m = 0; m < 2; ++m)
#pragma unroll
        for (int nd = 0; nd < 4; ++nd) Oacc[m][nd] = mfma16(pf[m], vf[nd], Oacc[m][nd]);
    }
  }

  int b = bh / H_, h = bh % H_;
#pragma unroll
  for (int m = 0; m < 2; ++m)
#pragma unroll
    for (int r = 0; r < 4; ++r) {
      float sv = lsum[m][r];
#pragma unroll
      for (int off = 1; off < 16; off <<= 1) sv += __shfl_xor(sv, off, 64);
      float inv = 1.0f / sv;
      int row = q0 + (m << 4) + rbase + r;
      size_t orow = ((size_t)b * N_ + row) * F_ + (size_t)h * DH_;
#pragma unroll
      for (int nd = 0; nd < 4; ++nd)
        Aout[orow + (nd << 4) + lr] = f2bu(Oacc[m][nd][r] * inv);
    }
}

extern "C" void kernel_launch(void* const* d_in, const int* in_sizes, int n_in,
                              void* d_out, int out_size, void* d_ws, size_t ws_size,
                              hipStream_t stream) {
  (void)in_sizes; (void)n_in; (void)out_size; (void)ws_size;
  const float* x   = (const float*)d_in[0];
  const float* Wq  = (const float*)d_in[1];
  const float* bq  = (const float*)d_in[2];
  const float* Wk  = (const float*)d_in[3];
  const float* bk  = (const float*)d_in[4];
  const float* Wv  = (const float*)d_in[5];
  const float* bv  = (const float*)d_in[6];
  const float* Wo  = (const float*)d_in[7];
  const float* bo  = (const float*)d_in[8];
  const float* g1  = (const float*)d_in[9];
  const float* bn1 = (const float*)d_in[10];
  const float* g2  = (const float*)d_in[11];
  const float* bn2 = (const float*)d_in[12];
  const float* W1  = (const float*)d_in[13];
  const float* b1  = (const float*)d_in[14];
  const float* W2  = (const float*)d_in[15];
  const float* b2  = (const float*)d_in[16];

  char* ws = (char*)d_ws;
  size_t off = 0;
  auto alloc = [&](size_t bytes) {
    char* p = ws + off;
    off += (bytes + 255) & ~(size_t)255;
    return p;
  };
  u16* Wqkvt = (u16*)alloc((size_t)3 * F_ * F_ * 2);   // [2304][768]
  u16* Wot  = (u16*)alloc((size_t)F_ * F_ * 2);
  u16* W1t  = (u16*)alloc((size_t)MH_ * F_ * 2);
  u16* W2t  = (u16*)alloc((size_t)MH_ * F_ * 2);
  float* bqkv = (float*)alloc((size_t)3 * F_ * 4);
  u16* xn  = (u16*)alloc((size_t)MROWS * F_ * 2);            // reused as hn
  u16* qb  = (u16*)alloc((size_t)B_ * H_ * N_ * DH_ * 2);    // 12582912 B
  u16* kb  = (u16*)alloc((size_t)B_ * H_ * N_ * DH_ * 2);
  u16* vb  = (u16*)alloc((size_t)B_ * H_ * N_ * DH_ * 2);
  u16* vt  = (u16*)alloc((size_t)B_ * H_ * N_ * DH_ * 2);
  u16* attn = (u16*)alloc((size_t)MROWS * F_ * 2);
  float* outb = (float*)alloc((size_t)MROWS * F_ * 4);
  u16* h1 = qb;   // q/k/v/vt region = 50331648 B = 8192*3072*2, free by then
  u16* hn = xn;

  // softmax scale folded into Q: 1/sqrt(768) * log2(e)
  const float QSCALE = 0.052058773227f;

  dim3 blk(256);
  transpose_bf16<float><<<dim3(12, 12, 1), blk, 0, stream>>>(Wq, Wqkvt, F_, F_);
  transpose_bf16<float><<<dim3(12, 12, 1), blk, 0, stream>>>(Wk, Wqkvt + (size_t)F_ * F_, F_, F_);
  transpose_bf16<float><<<dim3(12, 12, 1), blk, 0, stream>>>(Wv, Wqkvt + (size_t)2 * F_ * F_, F_, F_);
  transpose_bf16<float><<<dim3(12, 12, 1), blk, 0, stream>>>(Wo, Wot, F_, F_);
  transpose_bf16<float><<<dim3(48, 12, 1), blk, 0, stream>>>(W1, W1t, F_, MH_);
  transpose_bf16<float><<<dim3(12, 48, 1), blk, 0, stream>>>(W2, W2t, MH_, F_);
  concat_bias<<<dim3(9), blk, 0, stream>>>(bq, bk, bv, bqkv);
  ln_to_bf16<<<dim3(MROWS), blk, 0, stream>>>(x, g1, bn1, xn);
  gemm_bt<0><<<dim3(18 * 64), blk, 0, stream>>>(xn, Wqkvt, bqkv, qb, nullptr, 3 * F_, F_, QSCALE);
  transpose_bf16<u16><<<dim3(1, 16, 96), blk, 0, stream>>>(vb, vt, N_, DH_);
  attn_fwd<<<dim3(768), blk, 0, stream>>>(qb, kb, vt, attn);
  gemm_bt<1><<<dim3(6 * 64), blk, 0, stream>>>(attn, Wot, bo, outb, x, F_, F_, 1.0f);
  ln_to_bf16<<<dim3(MROWS), blk, 0, stream>>>(outb, g2, bn2, hn);
  gemm_bt<2><<<dim3(24 * 64), blk, 0, stream>>>(hn, W1t, b1, h1, nullptr, MH_, F_, 1.0f);
  gemm_bt<3><<<dim3(6 * 64), blk, 0, stream>>>(h1, W2t, b2, d_out, outb, F_, MH_, 1.0f);
}

// Round 4
// 317.000 us; speedup vs baseline: 1.5681x; 1.0054x over previous
//
#include <hip/hip_runtime.h>
#include <math.h>

#define B_ 8
#define N_ 1024
#define F_ 768
#define H_ 12
#define DH_ 64
#define MH_ 3072
#define MROWS (B_ * N_)

typedef unsigned short u16;
typedef unsigned int u32;
typedef __bf16 bf16x8 __attribute__((ext_vector_type(8)));
typedef float f32x4 __attribute__((ext_vector_type(4)));

__device__ inline f32x4 mfma16(bf16x8 a, bf16x8 b, f32x4 c) {
  return __builtin_amdgcn_mfma_f32_16x16x32_bf16(a, b, c, 0, 0, 0);
}

__device__ inline u16 f2bu(float f) {  // float -> bf16 bits, RNE
  u32 b = __builtin_bit_cast(u32, f);
  b += 0x7fffu + ((b >> 16) & 1u);
  return (u16)(b >> 16);
}
__device__ inline float bu2f(u16 u) {
  u32 x = ((u32)u) << 16;
  return __builtin_bit_cast(float, x);
}
__device__ inline float gelu_exact(float x) {
  return 0.5f * x * (1.0f + erff(x * 0.70710678118654752f));
}

#define AS1 __attribute__((address_space(1)))
#define AS3 __attribute__((address_space(3)))
__device__ inline void glds16(const void* g, void* l) {
  __builtin_amdgcn_global_load_lds((const AS1 void*)g, (AS3 void*)l, 16, 0, 0);
}

// ---------------- transpose + convert to bf16: out[c][r] = in[r][c] ----------
__device__ inline float ldf(const float* p) { return *p; }
__device__ inline float ldf(const u16* p) { return bu2f(*p); }

template <typename Tin>
__global__ __launch_bounds__(256) void transpose_bf16(
    const Tin* __restrict__ in, u16* __restrict__ out, int R, int C) {
  __shared__ float tile[64][65];
  size_t ibase = (size_t)blockIdx.z * (size_t)R * (size_t)C;
  size_t obase = (size_t)blockIdx.z * (size_t)R * (size_t)C;
  int r0 = blockIdx.y << 6, c0 = blockIdx.x << 6;
  int t = threadIdx.x;
#pragma unroll
  for (int i = 0; i < 16; ++i) {
    int idx = t + (i << 8);
    int r = idx >> 6, c = idx & 63;
    tile[r][c] = ldf(&in[ibase + (size_t)(r0 + r) * C + (c0 + c)]);
  }
  __syncthreads();
#pragma unroll
  for (int i = 0; i < 16; ++i) {
    int idx = t + (i << 8);
    int rr = idx >> 6, cc = idx & 63;
    out[obase + (size_t)(c0 + rr) * R + (r0 + cc)] = f2bu(tile[cc][rr]);
  }
}

// ---------------- concat 3 bias vectors [768] -> [2304] ----------------------
__global__ __launch_bounds__(256) void concat_bias(
    const float* __restrict__ a, const float* __restrict__ b,
    const float* __restrict__ c, float* __restrict__ o) {
  int i = blockIdx.x * 256 + threadIdx.x;
  if (i < 768) o[i] = a[i];
  else if (i < 1536) o[i] = b[i - 768];
  else o[i] = c[i - 1536];
}

// ---------------- LayerNorm (row=768) fp32 -> bf16 ---------------------------
__global__ __launch_bounds__(256) void ln_to_bf16(
    const float* __restrict__ X, const float* __restrict__ gw,
    const float* __restrict__ bw, u16* __restrict__ Y) {
  int row = blockIdx.x;
  int t = threadIdx.x;
  const float* xr = X + (size_t)row * F_;
  float v0 = xr[t], v1 = xr[t + 256], v2 = xr[t + 512];
  float s = v0 + v1 + v2;
  float ss = v0 * v0 + v1 * v1 + v2 * v2;
#pragma unroll
  for (int off = 1; off < 64; off <<= 1) {
    s += __shfl_xor(s, off, 64);
    ss += __shfl_xor(ss, off, 64);
  }
  __shared__ float red[8];
  int wid = t >> 6, lane = t & 63;
  if (lane == 0) { red[wid] = s; red[4 + wid] = ss; }
  __syncthreads();
  s = red[0] + red[1] + red[2] + red[3];
  ss = red[4] + red[5] + red[6] + red[7];
  float mu = s * (1.0f / F_);
  float var = ss * (1.0f / F_) - mu * mu;
  float rstd = rsqrtf(var + 1e-5f);
  u16* yr = Y + (size_t)row * F_;
  yr[t] = f2bu((v0 - mu) * rstd * gw[t] + bw[t]);
  yr[t + 256] = f2bu((v1 - mu) * rstd * gw[t + 256] + bw[t + 256]);
  yr[t + 512] = f2bu((v2 - mu) * rstd * gw[t + 512] + bw[t + 512]);
}

// ---------------- bf16 GEMM: counted-vmcnt 3-slot ring + swizzle -------------
// C = A[M,K] * Bt[N,K]^T + bias, fused epilogues.
// LDS layout per slot is LINEAR [128][32]; swizzle applied on the GLOBAL
// source address (inverse) and the ds_read address (forward): elem col
// ^= ((row&3)<<3). glds dest stays linear (rule 21).
// MODE 0: qkv fused -> bf16 scatter to q/k/v [B,H,N,DH]; q scaled by qscale
// MODE 1: proj -> fp32 out = acc + bias + resid
// MODE 2: ffn1 -> bf16 gelu(acc + bias)
// MODE 3: ffn2 -> fp32 gelu(acc + bias) + resid
template <int MODE>
__global__ __launch_bounds__(256) void gemm_bt(
    const u16* __restrict__ A, const u16* __restrict__ Bt,
    const float* __restrict__ bias, void* __restrict__ outp,
    const float* __restrict__ resid, int Ndim, int Kdim, float qscale) {
  __shared__ __attribute__((aligned(16))) u16 As[3][128][32];
  __shared__ __attribute__((aligned(16))) u16 Bs[3][128][32];
  int t = threadIdx.x;
  int lane = t & 63, wid = t >> 6;

  // XCD-chunked swizzle: each XCD owns a contiguous range of work ids
  int nwg = gridDim.x;
  int q8 = nwg >> 3;
  int bid = blockIdx.x;
  int swz = (bid & 7) * q8 + (bid >> 3);
  int nnt = Ndim >> 7;
  int mt = swz / nnt, nt = swz - mt * nnt;
  int row0 = mt << 7, col0 = nt << 7;

  int wr = (wid >> 1) << 6, wc = (wid & 1) << 6;
  int lr = lane & 15, lk = (lane >> 4) << 3;
  int lkA = lk ^ ((lr & 3) << 3);  // swizzled read col (row&3 == lr&3)
  int rbase = (lane >> 4) << 2;
  f32x4 zero = {0.f, 0.f, 0.f, 0.f};
  f32x4 acc[4][4];
#pragma unroll
  for (int m = 0; m < 4; ++m)
#pragma unroll
    for (int n = 0; n < 4; ++n) acc[m][n] = zero;

  // staging: wave-uniform LDS base wid*1024; HW scatters lane*16.
  // dest row = wid*16 + lane/4, dest col = (lane&3)*8 -> source col is
  // inverse-swizzled by ((row&3)<<3) = (((lane>>2)&3)<<3).
  int srow = (wid << 4) + (lane >> 2);          // 0..63
  int scol = ((lane & 3) << 3) ^ (((lane >> 2) & 3) << 3);
  const u16* Ag = A + (size_t)(row0 + srow) * Kdim + scol;
  const u16* Bg = Bt + (size_t)(col0 + srow) * Kdim + scol;
  char* AsB = (char*)&As[0][0][0] + (wid << 10);
  char* BsB = (char*)&Bs[0][0][0] + (wid << 10);
  size_t half = (size_t)64 * Kdim;

  auto STAGE = [&](int slot, int kt) {
    int bo = slot << 13;
    glds16(Ag + kt, AsB + bo);
    glds16(Ag + kt + half, AsB + bo + 4096);
    glds16(Bg + kt, BsB + bo);
    glds16(Bg + kt + half, BsB + bo + 4096);
  };

  int nk = Kdim >> 5;
  STAGE(0, 0);
  if (nk > 1) STAGE(1, 32);
  int sl0 = 0, sl1 = 1, sl2 = 2;
  for (int i = 0; i < nk; ++i) {
    if (i + 1 < nk) {
      asm volatile("s_waitcnt vmcnt(4)" ::: "memory");
    } else {
      asm volatile("s_waitcnt vmcnt(0)" ::: "memory");
    }
    __builtin_amdgcn_sched_barrier(0);
    __builtin_amdgcn_s_barrier();
    __builtin_amdgcn_sched_barrier(0);
    if (i + 2 < nk) STAGE(sl2, (i + 2) << 5);
    bf16x8 af[4], bfr[4];
#pragma unroll
    for (int m = 0; m < 4; ++m) af[m] = *(const bf16x8*)&As[sl0][wr + (m << 4) + lr][lkA];
#pragma unroll
    for (int n = 0; n < 4; ++n) bfr[n] = *(const bf16x8*)&Bs[sl0][wc + (n << 4) + lr][lkA];
    __builtin_amdgcn_s_setprio(1);
#pragma unroll
    for (int m = 0; m < 4; ++m)
#pragma unroll
      for (int n = 0; n < 4; ++n) acc[m][n] = mfma16(af[m], bfr[n], acc[m][n]);
    __builtin_amdgcn_s_setprio(0);
    int tmp = sl0; sl0 = sl1; sl1 = sl2; sl2 = tmp;
  }

#pragma unroll
  for (int n = 0; n < 4; ++n) {
    int col = col0 + wc + (n << 4) + lr;
    float bc = bias[col];
    int sub = 0, hh = 0, dh = 0;
    float sc = 1.0f;
    if constexpr (MODE == 0) {
      sub = (col >= 1536) ? 2 : (col >= 768 ? 1 : 0);
      int c = col - sub * 768;
      hh = c >> 6; dh = c & 63;
      sc = (sub == 0) ? qscale : 1.0f;
    }
#pragma unroll
    for (int m = 0; m < 4; ++m) {
#pragma unroll
      for (int r = 0; r < 4; ++r) {
        int row = row0 + wr + (m << 4) + rbase + r;
        float val = acc[m][n][r] + bc;
        if constexpr (MODE == 0) {
          int b = row >> 10, nn = row & 1023;
          ((u16*)outp)[(size_t)sub * 6291456 +
                       ((((size_t)b * H_ + hh) << 10) + nn) * DH_ + dh] = f2bu(val * sc);
        } else if constexpr (MODE == 1) {
          val += resid[(size_t)row * Ndim + col];
          ((float*)outp)[(size_t)row * Ndim + col] = val;
        } else if constexpr (MODE == 2) {
          ((u16*)outp)[(size_t)row * Ndim + col] = f2bu(gelu_exact(val));
        } else {
          val = gelu_exact(val) + resid[(size_t)row * Ndim + col];
          ((float*)outp)[(size_t)row * Ndim + col] = val;
        }
      }
    }
  }
}

// ---------------- flash attention: no-max softmax, KV chunk 64, T14 split ----
// Q pre-scaled by 1/sqrt(768)*log2(e). Q,K [bh][N][64], Vt [bh][64][N].
__global__ __launch_bounds__(256, 3) void attn_fwd(
    const u16* __restrict__ Q, const u16* __restrict__ K,
    const u16* __restrict__ Vt, u16* __restrict__ Aout) {
  __shared__ __attribute__((aligned(16))) u16 Ks[64][72];
  __shared__ __attribute__((aligned(16))) u16 Vs[64][72];
  __shared__ __attribute__((aligned(16))) u16 Ps[4][32][72];
  int t = threadIdx.x, lane = t & 63, wid = t >> 6;

  int bid = blockIdx.x;                 // 768 blocks
  int swz = (bid & 7) * 96 + (bid >> 3);
  int bh = swz >> 3;
  int qt = swz & 7;
  int q0 = (qt << 7) + (wid << 5);

  int lr = lane & 15, lk = (lane >> 4) << 3;
  int rbase = (lane >> 4) << 2;

  bf16x8 qf[2][2];
#pragma unroll
  for (int m = 0; m < 2; ++m)
#pragma unroll
    for (int ks = 0; ks < 2; ++ks)
      qf[m][ks] = *(const bf16x8*)&Q[((size_t)bh * N_ + q0 + (m << 4) + lr) * DH_ + (ks << 5) + lk];

  float lsum[2][4];
  f32x4 zero = {0.f, 0.f, 0.f, 0.f};
  f32x4 Oacc[2][4];
#pragma unroll
  for (int m = 0; m < 2; ++m) {
#pragma unroll
    for (int r = 0; r < 4; ++r) lsum[m][r] = 0.f;
#pragma unroll
    for (int nd = 0; nd < 4; ++nd) Oacc[m][nd] = zero;
  }

  int srow = t >> 3;            // 0..31
  int scol = (t & 7) << 3;      // 0..56
  const u16* Kg = K + ((size_t)bh * N_ + srow) * DH_ + scol;
  const u16* Vg = Vt + ((size_t)bh * DH_ + srow) * N_ + scol;

  // T14 async-stage: loads for tile kt+1 issued during tile kt's compute
  uint4 kr0, kr1, vr0, vr1;
  auto LOADKV = [&](int kt) {
    kr0 = *(const uint4*)(Kg + (size_t)(kt << 6) * DH_);
    kr1 = *(const uint4*)(Kg + (size_t)((kt << 6) + 32) * DH_);
    vr0 = *(const uint4*)(Vg + (kt << 6));
    vr1 = *(const uint4*)(Vg + (size_t)32 * N_ + (kt << 6));
  };
  LOADKV(0);

  for (int kt = 0; kt < 16; ++kt) {
    __syncthreads();
    *(uint4*)&Ks[srow][scol]      = kr0;
    *(uint4*)&Ks[srow + 32][scol] = kr1;
    *(uint4*)&Vs[srow][scol]      = vr0;
    *(uint4*)&Vs[srow + 32][scol] = vr1;
    if (kt + 1 < 16) LOADKV(kt + 1);
    __syncthreads();

    f32x4 s[2][4];
#pragma unroll
    for (int m = 0; m < 2; ++m)
#pragma unroll
      for (int n = 0; n < 4; ++n) s[m][n] = zero;
#pragma unroll
    for (int ks = 0; ks < 2; ++ks) {
      bf16x8 kf[4];
#pragma unroll
      for (int n = 0; n < 4; ++n) kf[n] = *(const bf16x8*)&Ks[(n << 4) + lr][(ks << 5) + lk];
#pragma unroll
      for (int m = 0; m < 2; ++m)
#pragma unroll
        for (int n = 0; n < 4; ++n) s[m][n] = mfma16(qf[m][ks], kf[n], s[m][n]);
    }

#pragma unroll
    for (int m = 0; m < 2; ++m)
#pragma unroll
      for (int n = 0; n < 4; ++n)
#pragma unroll
        for (int r = 0; r < 4; ++r) {
          float p = exp2f(s[m][n][r]);
          lsum[m][r] += p;
          Ps[wid][(m << 4) + rbase + r][(n << 4) + lr] = f2bu(p);
        }

#pragma unroll
    for (int ks = 0; ks < 2; ++ks) {
      bf16x8 pf[2], vf[4];
#pragma unroll
      for (int m = 0; m < 2; ++m) pf[m] = *(const bf16x8*)&Ps[wid][(m << 4) + lr][(ks << 5) + lk];
#pragma unroll
      for (int nd = 0; nd < 4; ++nd) vf[nd] = *(const bf16x8*)&Vs[(nd << 4) + lr][(ks << 5) + lk];
#pragma unroll
      for (int m = 0; m < 2; ++m)
#pragma unroll
        for (int nd = 0; nd < 4; ++nd) Oacc[m][nd] = mfma16(pf[m], vf[nd], Oacc[m][nd]);
    }
  }

  int b = bh / H_, h = bh % H_;
#pragma unroll
  for (int m = 0; m < 2; ++m)
#pragma unroll
    for (int r = 0; r < 4; ++r) {
      float sv = lsum[m][r];
#pragma unroll
      for (int off = 1; off < 16; off <<= 1) sv += __shfl_xor(sv, off, 64);
      float inv = 1.0f / sv;
      int row = q0 + (m << 4) + rbase + r;
      size_t orow = ((size_t)b * N_ + row) * F_ + (size_t)h * DH_;
#pragma unroll
      for (int nd = 0; nd < 4; ++nd)
        Aout[orow + (nd << 4) + lr] = f2bu(Oacc[m][nd][r] * inv);
    }
}

extern "C" void kernel_launch(void* const* d_in, const int* in_sizes, int n_in,
                              void* d_out, int out_size, void* d_ws, size_t ws_size,
                              hipStream_t stream) {
  (void)in_sizes; (void)n_in; (void)out_size; (void)ws_size;
  const float* x   = (const float*)d_in[0];
  const float* Wq  = (const float*)d_in[1];
  const float* bq  = (const float*)d_in[2];
  const float* Wk  = (const float*)d_in[3];
  const float* bk  = (const float*)d_in[4];
  const float* Wv  = (const float*)d_in[5];
  const float* bv  = (const float*)d_in[6];
  const float* Wo  = (const float*)d_in[7];
  const float* bo  = (const float*)d_in[8];
  const float* g1  = (const float*)d_in[9];
  const float* bn1 = (const float*)d_in[10];
  const float* g2  = (const float*)d_in[11];
  const float* bn2 = (const float*)d_in[12];
  const float* W1  = (const float*)d_in[13];
  const float* b1  = (const float*)d_in[14];
  const float* W2  = (const float*)d_in[15];
  const float* b2  = (const float*)d_in[16];

  char* ws = (char*)d_ws;
  size_t off = 0;
  auto alloc = [&](size_t bytes) {
    char* p = ws + off;
    off += (bytes + 255) & ~(size_t)255;
    return p;
  };
  u16* Wqkvt = (u16*)alloc((size_t)3 * F_ * F_ * 2);   // [2304][768]
  u16* Wot  = (u16*)alloc((size_t)F_ * F_ * 2);
  u16* W1t  = (u16*)alloc((size_t)MH_ * F_ * 2);
  u16* W2t  = (u16*)alloc((size_t)MH_ * F_ * 2);
  float* bqkv = (float*)alloc((size_t)3 * F_ * 4);
  u16* xn  = (u16*)alloc((size_t)MROWS * F_ * 2);            // reused as hn
  u16* qb  = (u16*)alloc((size_t)B_ * H_ * N_ * DH_ * 2);    // 12582912 B
  u16* kb  = (u16*)alloc((size_t)B_ * H_ * N_ * DH_ * 2);
  u16* vb  = (u16*)alloc((size_t)B_ * H_ * N_ * DH_ * 2);
  u16* vt  = (u16*)alloc((size_t)B_ * H_ * N_ * DH_ * 2);
  u16* attn = (u16*)alloc((size_t)MROWS * F_ * 2);
  float* outb = (float*)alloc((size_t)MROWS * F_ * 4);
  u16* h1 = qb;   // q/k/v/vt region = 50331648 B = 8192*3072*2, free by then
  u16* hn = xn;

  // softmax scale folded into Q: 1/sqrt(768) * log2(e)
  const float QSCALE = 0.052058773227f;

  dim3 blk(256);
  transpose_bf16<float><<<dim3(12, 12, 1), blk, 0, stream>>>(Wq, Wqkvt, F_, F_);
  transpose_bf16<float><<<dim3(12, 12, 1), blk, 0, stream>>>(Wk, Wqkvt + (size_t)F_ * F_, F_, F_);
  transpose_bf16<float><<<dim3(12, 12, 1), blk, 0, stream>>>(Wv, Wqkvt + (size_t)2 * F_ * F_, F_, F_);
  transpose_bf16<float><<<dim3(12, 12, 1), blk, 0, stream>>>(Wo, Wot, F_, F_);
  transpose_bf16<float><<<dim3(48, 12, 1), blk, 0, stream>>>(W1, W1t, F_, MH_);
  transpose_bf16<float><<<dim3(12, 48, 1), blk, 0, stream>>>(W2, W2t, MH_, F_);
  concat_bias<<<dim3(9), blk, 0, stream>>>(bq, bk, bv, bqkv);
  ln_to_bf16<<<dim3(MROWS), blk, 0, stream>>>(x, g1, bn1, xn);
  gemm_bt<0><<<dim3(18 * 64), blk, 0, stream>>>(xn, Wqkvt, bqkv, qb, nullptr, 3 * F_, F_, QSCALE);
  transpose_bf16<u16><<<dim3(1, 16, 96), blk, 0, stream>>>(vb, vt, N_, DH_);
  attn_fwd<<<dim3(768), blk, 0, stream>>>(qb, kb, vt, attn);
  gemm_bt<1><<<dim3(6 * 64), blk, 0, stream>>>(attn, Wot, bo, outb, x, F_, F_, 1.0f);
  ln_to_bf16<<<dim3(MROWS), blk, 0, stream>>>(outb, g2, bn2, hn);
  gemm_bt<2><<<dim3(24 * 64), blk, 0, stream>>>(hn, W1t, b1, h1, nullptr, MH_, F_, 1.0f);
  gemm_bt<3><<<dim3(6 * 64), blk, 0, stream>>>(h1, W2t, b2, d_out, outb, F_, MH_, 1.0f);
}